// Round 3
// baseline (253.006 us; speedup 1.0000x reference)
//
#include <hip/hip_runtime.h>
#include <math.h>

// Problem constants
#define KCODES 1024
#define DDIM   64

// Output layout (floats), reference return order.
constexpr size_t O_ZQ  = 0;
constexpr size_t O_IDX = 4194304;
constexpr size_t O_EMB = O_IDX + 65536;   // 4259840
constexpr size_t O_EMA = O_EMB + 65536;   // 4325376
constexpr size_t O_CEN = O_EMA + 65536;   // 4390912

// Workspace layout (float offsets)
constexpr size_t W_UPD   = 0;               // [K][D] segment-sum accumulator
constexpr size_t W_CNT   = 65536;           // [K] histogram
constexpr size_t W_ENORM = 66560;           // [K] ||e_k||^2 (fp32 exact)
constexpr size_t W_EN2   = 67584;           // [K] -0.5*||e_k||^2 (acc-init fold)
constexpr size_t W_EMAXA = 68608;           // [16] per-prep-block max ||e||^2
constexpr size_t W_FLAGN = 68624;           // int: ambiguous-row count
constexpr size_t W_DONE  = 68640;           // int: done-block counter (fusion)
constexpr size_t W_FLAGL = 68656;           // [FLAGCAP] int row ids
constexpr int    FLAGCAP = 8192;
constexpr size_t W_EMBT  = 76848;           // [K][D] codebook fp32 (transposed)
constexpr size_t W_G16H  = 142384;          // [16 chunks][64 codes][64d] f16 hi, PRE-SWIZZLED
constexpr size_t W_G16L  = 175152;          // same, f16 lo. end = 207920 floats

typedef _Float16 f16;
typedef f16 f16x8 __attribute__((ext_vector_type(8)));
typedef float f32x4 __attribute__((ext_vector_type(4)));

#define MF(a, b, c) __builtin_amdgcn_mfma_f32_16x16x32_f16((a), (b), (c), 0, 0, 0)

static __device__ __forceinline__ void gload16(const void* g, void* l) {
  __builtin_amdgcn_global_load_lds(
      (const __attribute__((address_space(1))) void*)g,
      (__attribute__((address_space(3))) void*)l, 16, 0, 0);
}

// ---------------------------------------------------------------------------
// K1: transpose emb -> embT fp32; f16 hi/lo split written PRE-SWIZZLED so a
// linear global_load_lds copy yields the XOR-swizzled LDS image (m173
// pattern); eNorm, en2=-0.5*eNorm, per-block emax; zero upd/cnt/flagn/done.
__global__ __launch_bounds__(256) void vq_prep(const float* __restrict__ emb,
                                               float* __restrict__ ws) {
  __shared__ float t_lds[64 * 65];          // [d][k] padded (+1)
  const int tid = threadIdx.x;
  const int g   = blockIdx.x;
  const int k0  = g * 64;

  #pragma unroll
  for (int it = 0; it < 16; ++it) {
    const int idx = tid + it * 256;         // 0..4095
    const int d   = idx >> 6;
    const int kq  = idx & 63;
    t_lds[d * 65 + kq] = emb[d * KCODES + k0 + kq];
  }
  __syncthreads();

  f16* gh = (f16*)(ws + W_G16H);
  f16* gl = (f16*)(ws + W_G16L);
  #pragma unroll
  for (int it = 0; it < 16; ++it) {
    const int idx = tid + it * 256;
    const int kk  = idx >> 6;               // local code 0..63
    const int d   = idx & 63;
    const float v = t_lds[d * 65 + kk];
    ws[W_EMBT + (size_t)(k0 + kk) * 64 + d] = v;
    const f16 hi = (f16)v;
    const f16 lo = (f16)(v - (float)hi);
    // swizzled 16B-unit index: u = (d>>3) ^ (kk&7)
    const int u  = (d >> 3) ^ (kk & 7);
    const size_t fo = (size_t)g * 4096 + kk * 64 + u * 8 + (d & 7);
    gh[fo] = hi;
    gl[fo] = lo;
  }

  if (tid < 64) {
    const int k = tid;
    float s = 0.f;
    #pragma unroll
    for (int d = 0; d < DDIM; ++d) {
      const float v = t_lds[d * 65 + k];
      s = fmaf(v, v, s);
    }
    ws[W_ENORM + k0 + k] = s;
    ws[W_EN2   + k0 + k] = -0.5f * s;
    float mx = s;
    #pragma unroll
    for (int off = 1; off < 64; off <<= 1) mx = fmaxf(mx, __shfl_xor(mx, off, 64));
    if (tid == 0) ws[W_EMAXA + g] = mx;
  }

  float4* u4 = (float4*)(ws + W_UPD);
  #pragma unroll
  for (int j = 0; j < 4; ++j) u4[g * 1024 + tid + j * 256] = float4{0.f, 0.f, 0.f, 0.f};
  if (tid < 64) ws[W_CNT + k0 + tid] = 0.f;
  if (g == 0 && tid == 0) {
    ((int*)(ws + W_FLAGN))[0] = 0;
    ((int*)(ws + W_DONE))[0]  = 0;
  }
}

// ---------------------------------------------------------------------------
// K2: MFMA distance GEMM (3-term f16 split, verified round 2) + certified
// argmin + fused epilogue. 512 blocks x 256 thr; block = 128 rows x full K.
// Each wave owns TWO 16-row sets sharing one set of A-frag LDS reads (halves
// LDS-pipe load). e-tiles: 64-code chunks, double-buffered, staged by
// global_load_lds from the pre-swizzled global tables; ONE barrier per chunk
// with next chunk's loads issued before compute (m97 structure).
// en2 = -0.5*||e||^2 folded into acc init -> argmin == max(acc), no per-
// candidate fma. Margin (identical to round 2): accept iff
// 2*(M1-M2) > 1e-4*||z||*sqrt(emax); else defer to exact rescore.
#define ZP 132
__global__ __launch_bounds__(256, 2) void vq_main(
    const float* __restrict__ z_e,
    const float* __restrict__ g16h,   // ws + W_G16H (pre-swizzled f16 hi)
    const float* __restrict__ g16l,   // ws + W_G16L (pre-swizzled f16 lo)
    const float* __restrict__ embT,   // ws + W_EMBT [K][D] fp32 (epilogue A)
    const float* __restrict__ en2,    // ws + W_EN2  [K]
    const float* __restrict__ emaxa,  // ws + W_EMAXA [16]
    float* __restrict__ upd,
    float* __restrict__ cnt,
    int*   __restrict__ flagn,
    int*   __restrict__ flagl,
    float* __restrict__ out) {
  __shared__ float z_lds[DDIM * ZP];                 // [d][row], fp32
  __shared__ __align__(16) f16 e_hi[2][4096];        // dbuf: 64 codes x 64d
  __shared__ __align__(16) f16 e_lo[2][4096];
  __shared__ __align__(16) float en2_lds[KCODES];    // -0.5*||e||^2, all codes
  __shared__ int bidx[128];

  const int tid  = threadIdx.x;
  const int bid  = blockIdx.x;
  const int wv   = tid >> 6;
  const int lane = tid & 63;
  const int m    = lane & 15;
  const int q    = lane >> 4;
  const int r0   = wv * 32 + m;        // set0 row
  const int r1   = r0 + 16;            // set1 row

  const int n0  = bid * 128;
  const int b   = n0 >> 12;
  const int hw0 = n0 & 4095;
  const size_t zbase = (size_t)b * 262144 + (size_t)hw0;

  // ---- issue chunk-0 e-loads first (overlap with z staging) ----
  {
    const char* sh = (const char*)g16h + (size_t)(wv * 2) * 1024 + lane * 16;
    const char* sl = (const char*)g16l + (size_t)(wv * 2) * 1024 + lane * 16;
    char* dh = (char*)&e_hi[0][0] + (wv * 2) * 1024;
    char* dl = (char*)&e_lo[0][0] + (wv * 2) * 1024;
    gload16(sh, dh);           gload16(sh + 1024, dh + 1024);
    gload16(sl, dl);           gload16(sl + 1024, dl + 1024);
  }

  // ---- stage z tile [64d][128r] fp32 (coalesced), kept for epilogues ----
  {
    const float4* z4 = (const float4*)(z_e + zbase);
    #pragma unroll
    for (int it = 0; it < 8; ++it) {
      const int f  = tid + it * 256;   // 0..2047
      const int d  = f >> 5;
      const int r4 = f & 31;
      const float4 v = z4[(size_t)d * 1024 + r4];
      *(float4*)(z_lds + d * ZP + r4 * 4) = v;
    }
  }
  // ---- stage en2 (all 1024 codes, 4KB) ----
  ((float4*)en2_lds)[tid] = ((const float4*)en2)[tid];

  // ---- emax (global max over codebook, precomputed per prep-block) ----
  float emax = 0.f;
  {
    const float4* e4 = (const float4*)emaxa;
    #pragma unroll
    for (int i = 0; i < 4; ++i) {
      const float4 v = e4[i];
      emax = fmaxf(emax, fmaxf(fmaxf(v.x, v.y), fmaxf(v.z, v.w)));
    }
  }
  __syncthreads();   // z_lds + en2_lds + chunk0 ready (implicit vmcnt(0))

  // ---- build B-frags hi/lo for both row-sets + exact row norms ----
  f16x8 b0h_0, b1h_0, b0l_0, b1l_0, b0h_1, b1h_1, b0l_1, b1l_1;
  float zz0 = 0.f, zz1 = 0.f;
  #pragma unroll
  for (int j = 0; j < 8; ++j) {
    const int d0 = q * 8 + j, d1 = 32 + q * 8 + j;
    const float v00 = z_lds[d0 * ZP + r0];
    const float v01 = z_lds[d1 * ZP + r0];
    const float v10 = z_lds[d0 * ZP + r1];
    const float v11 = z_lds[d1 * ZP + r1];
    zz0 = fmaf(v00, v00, zz0); zz0 = fmaf(v01, v01, zz0);
    zz1 = fmaf(v10, v10, zz1); zz1 = fmaf(v11, v11, zz1);
    const f16 h00 = (f16)v00, h01 = (f16)v01, h10 = (f16)v10, h11 = (f16)v11;
    b0h_0[j] = h00; b1h_0[j] = h01; b0h_1[j] = h10; b1h_1[j] = h11;
    b0l_0[j] = (f16)(v00 - (float)h00);
    b1l_0[j] = (f16)(v01 - (float)h01);
    b0l_1[j] = (f16)(v10 - (float)h10);
    b1l_1[j] = (f16)(v11 - (float)h11);
  }
  zz0 += __shfl_xor(zz0, 16, 64); zz0 += __shfl_xor(zz0, 32, 64);
  zz1 += __shfl_xor(zz1, 16, 64); zz1 += __shfl_xor(zz1, 32, 64);

  // A-frag swizzled byte offsets (code m within 16-tile; units q and 4+q)
  const int lcl7  = m & 7;
  const int aoff0 = m * 128 + ((q)     ^ lcl7) * 16;
  const int aoff1 = m * 128 + ((4 + q) ^ lcl7) * 16;

  float M1_0 = -INFINITY, M2_0 = -INFINITY, M1_1 = -INFINITY, M2_1 = -INFINITY;
  int   I1_0 = 0, I1_1 = 0;

  #pragma unroll 1
  for (int c = 0; c < 16; ++c) {
    const int cb = c & 1;
    if (c < 15) {   // issue next chunk's loads (land before end-of-iter barrier)
      const int nb = cb ^ 1;
      const size_t so = (size_t)(c + 1) * 8192 + (wv * 2) * 1024 + lane * 16;
      const char* sh = (const char*)g16h + so;
      const char* sl = (const char*)g16l + so;
      char* dh = (char*)&e_hi[nb][0] + (wv * 2) * 1024;
      char* dl = (char*)&e_lo[nb][0] + (wv * 2) * 1024;
      gload16(sh, dh);           gload16(sh + 1024, dh + 1024);
      gload16(sl, dl);           gload16(sl + 1024, dl + 1024);
    }
    const char* eb = (const char*)&e_hi[cb][0];
    const char* lb = (const char*)&e_lo[cb][0];
    #pragma unroll
    for (int t = 0; t < 4; ++t) {
      const f16x8 a0h = *(const f16x8*)(eb + t * 2048 + aoff0);
      const f16x8 a1h = *(const f16x8*)(eb + t * 2048 + aoff1);
      const f16x8 a0l = *(const f16x8*)(lb + t * 2048 + aoff0);
      const f16x8 a1l = *(const f16x8*)(lb + t * 2048 + aoff1);
      const f32x4 en2f = *(const f32x4*)(en2_lds + c * 64 + t * 16 + q * 4);
      f32x4 acc0 = en2f, acc1 = en2f;
      acc0 = MF(a0l, b0h_0, acc0);  acc1 = MF(a0l, b0h_1, acc1);
      acc0 = MF(a1l, b1h_0, acc0);  acc1 = MF(a1l, b1h_1, acc1);
      acc0 = MF(a0h, b0l_0, acc0);  acc1 = MF(a0h, b0l_1, acc1);
      acc0 = MF(a1h, b1l_0, acc0);  acc1 = MF(a1h, b1l_1, acc1);
      acc0 = MF(a0h, b0h_0, acc0);  acc1 = MF(a0h, b0h_1, acc1);
      acc0 = MF(a1h, b1h_0, acc0);  acc1 = MF(a1h, b1h_1, acc1);
      const int ib = c * 64 + t * 16 + q * 4;
      #pragma unroll
      for (int r = 0; r < 4; ++r) {
        const float a = acc0[r];
        const bool gt = a > M1_0;
        M2_0 = fmaxf(M2_0, fminf(a, M1_0));
        if (gt) I1_0 = ib + r;
        M1_0 = fmaxf(M1_0, a);
        const float a1v = acc1[r];
        const bool gt1 = a1v > M1_1;
        M2_1 = fmaxf(M2_1, fminf(a1v, M1_1));
        if (gt1) I1_1 = ib + r;
        M1_1 = fmaxf(M1_1, a1v);
      }
    }
    __syncthreads();   // drains next-chunk loads; protects dbuf swap
  }

  // ---- merge (M1,I1,M2) across the 4 code-subgroups (lane bits 4,5) ----
  #pragma unroll
  for (int off = 16; off <= 32; off <<= 1) {
    {
      const float o1 = __shfl_xor(M1_0, off, 64);
      const float o2 = __shfl_xor(M2_0, off, 64);
      const int   oi = __shfl_xor(I1_0, off, 64);
      const float nm2 = fmaxf(fmaxf(M2_0, o2), fminf(M1_0, o1));
      if (o1 > M1_0) I1_0 = oi;
      M1_0 = fmaxf(M1_0, o1);
      M2_0 = nm2;
    }
    {
      const float o1 = __shfl_xor(M1_1, off, 64);
      const float o2 = __shfl_xor(M2_1, off, 64);
      const int   oi = __shfl_xor(I1_1, off, 64);
      const float nm2 = fmaxf(fmaxf(M2_1, o2), fminf(M1_1, o1));
      if (o1 > M1_1) I1_1 = oi;
      M1_1 = fmaxf(M1_1, o1);
      M2_1 = nm2;
    }
  }

  if (lane < 32) {   // lanes 0..15 write set0 rows, 16..31 write set1 rows
    const int s   = lane >> 4;
    const int row = wv * 32 + s * 16 + m;
    const float MM1 = s ? M1_1 : M1_0;
    const float MM2 = s ? M2_1 : M2_0;
    const int   II  = s ? I1_1 : I1_0;
    const float zzv = s ? zz1 : zz0;
    // dist gap = 2*(M1-M2); accept iff > 1e-4*||z||*sqrt(emax)
    const float Mh = 5.0e-5f * sqrtf(zzv * emax);
    if (MM1 - MM2 > Mh) {
      bidx[row] = II;
      out[O_IDX + n0 + row] = (float)II;
      atomicAdd(cnt + II, 1.0f);
    } else {
      bidx[row] = -1;                     // defer to exact rescore
      const int sl = atomicAdd(flagn, 1);
      if (sl < FLAGCAP) flagl[sl] = n0 + row;
    }
  }
  __syncthreads();

  // ---- epilogue A: z_q = z + (e - z); coalesced over rows ----
  {
    const int row  = tid & 127;
    const int half = tid >> 7;            // 2 halves x 32 d
    const int code = bidx[row];
    if (code >= 0) {
      const float4* er4 = (const float4*)(embT + (size_t)code * 64);
      #pragma unroll
      for (int qq = 0; qq < 8; ++qq) {
        const float4 e4 = er4[half * 8 + qq];
        const float ev[4] = {e4.x, e4.y, e4.z, e4.w};
        #pragma unroll
        for (int x = 0; x < 4; ++x) {
          const int d = half * 32 + qq * 4 + x;
          const float zv = z_lds[d * ZP + row];
          out[O_ZQ + zbase + (size_t)d * 4096 + row] = zv + (ev[x] - zv);
        }
      }
    }
  }

  // ---- epilogue B: segment-sum; one coalesced atomic instr per row ----
  {
    #pragma unroll 4
    for (int rr = 0; rr < 32; ++rr) {
      const int row  = wv * 32 + rr;
      const int code = bidx[row];
      if (code >= 0)
        atomicAdd(upd + (size_t)code * 64 + lane, z_lds[lane * ZP + row]);
    }
  }
}

// ---------------------------------------------------------------------------
// K3: exact fp32 rescore (one row per block, codes-parallel — identical logic
// to round 2) FUSED with the EMA/normalize finalization: after all blocks
// finish rescoring, the LAST block (fence + done-counter, no spin) runs the
// final pass. Saves one kernel launch.
__global__ __launch_bounds__(256) void vq_rescore_final(
    const float* __restrict__ z_e,
    const float* __restrict__ embT,
    const float* __restrict__ eN,
    const int* __restrict__ flagn,
    const int* __restrict__ flagl,
    float* __restrict__ upd,
    float* __restrict__ cnt,
    const float* __restrict__ emb_ema,
    const float* __restrict__ counts_ema,
    int* __restrict__ done,
    float* __restrict__ out) {
  __shared__ float zrow[64];
  __shared__ float wv_v[4];
  __shared__ int   wv_i[4];
  __shared__ int   bestc;
  __shared__ int   lastf;
  __shared__ float red[256];

  const int tid = threadIdx.x;
  int nf = *flagn;
  if (nf > FLAGCAP) nf = FLAGCAP;

  for (int j = blockIdx.x; j < nf; j += gridDim.x) {
    __syncthreads();   // protect zrow/bestc reuse across iterations
    const int rowid = flagl[j];
    const int bb = rowid >> 12;
    const int hw = rowid & 4095;
    const size_t base = (size_t)bb * 262144 + (size_t)hw;
    if (tid < 64) zrow[tid] = z_e[base + (size_t)tid * 4096];
    __syncthreads();

    // 4 ascending codes per thread; strict < keeps lowest index
    float bm = INFINITY;
    int   bi = 0;
    #pragma unroll
    for (int cc = 0; cc < 4; ++cc) {
      const int k = tid * 4 + cc;
      const float4* e4p = (const float4*)(embT + (size_t)k * 64);
      float a0 = 0.f, a1 = 0.f, a2 = 0.f, a3 = 0.f;
      #pragma unroll
      for (int d4 = 0; d4 < 16; ++d4) {
        const float4 e4 = e4p[d4];
        a0 = fmaf(zrow[d4 * 4 + 0], e4.x, a0);
        a1 = fmaf(zrow[d4 * 4 + 1], e4.y, a1);
        a2 = fmaf(zrow[d4 * 4 + 2], e4.z, a2);
        a3 = fmaf(zrow[d4 * 4 + 3], e4.w, a3);
      }
      const float dist = fmaf(-2.f, (a0 + a1) + (a2 + a3), eN[k]);
      if (dist < bm) { bm = dist; bi = k; }
    }
    #pragma unroll
    for (int mm = 1; mm < 64; mm <<= 1) {
      const float v2 = __shfl_xor(bm, mm, 64);
      const int   i2 = __shfl_xor(bi, mm, 64);
      if (v2 < bm || (v2 == bm && i2 < bi)) { bm = v2; bi = i2; }
    }
    if ((tid & 63) == 0) { wv_v[tid >> 6] = bm; wv_i[tid >> 6] = bi; }
    __syncthreads();
    if (tid == 0) {
      float v = wv_v[0]; int ix = wv_i[0];
      #pragma unroll
      for (int w = 1; w < 4; ++w) {
        if (wv_v[w] < v || (wv_v[w] == v && wv_i[w] < ix)) { v = wv_v[w]; ix = wv_i[w]; }
      }
      bestc = ix;
      out[O_IDX + rowid] = (float)ix;
      atomicAdd(cnt + ix, 1.0f);
    }
    __syncthreads();
    if (tid < 64) {
      const int d = tid;
      const float zv = zrow[d];
      const float ev = embT[(size_t)bestc * 64 + d];
      out[O_ZQ + base + (size_t)d * 4096] = zv + (ev - zv);
      atomicAdd(upd + (size_t)bestc * 64 + d, zv);
    }
  }

  // ---- fused finalization: last block to finish does the EMA pass ----
  __syncthreads();
  __threadfence();
  if (tid == 0) {
    const int my = atomicAdd(done, 1);
    lastf = (my == (int)gridDim.x - 1) ? 1 : 0;
  }
  __syncthreads();
  if (lastf) {
    __threadfence();
    float psum = 0.f;
    for (int t = tid; t < KCODES; t += 256) {
      const float ce  = counts_ema[t];
      const float cen = ce + 0.01f * (cnt[t] - ce);
      psum += cen;
      out[O_CEN + t] = cen;
    }
    red[tid] = psum;
    __syncthreads();
    #pragma unroll
    for (int s = 128; s > 0; s >>= 1) {
      if (tid < s) red[tid] += red[tid + s];
      __syncthreads();
    }
    const float nsum = red[0];
    for (int i = tid; i < 65536; i += 256) {
      const int d = i >> 10;
      const int k = i & 1023;
      const float ce  = counts_ema[k];
      const float cen = ce + 0.01f * (cnt[k] - ce);
      const float norm = (cen + 1e-5f) / (nsum + (float)KCODES * 1e-5f) * nsum;
      const float ema     = emb_ema[i];
      const float ema_new = ema + 0.01f * (upd[(size_t)k * 64 + d] - ema);
      out[O_EMA + i] = ema_new;
      out[O_EMB + i] = ema_new / norm;
    }
  }
}

// ---------------------------------------------------------------------------
extern "C" void kernel_launch(void* const* d_in, const int* in_sizes, int n_in,
                              void* d_out, int out_size, void* d_ws, size_t ws_size,
                              hipStream_t stream) {
  const float* z_e        = (const float*)d_in[0];
  const float* emb        = (const float*)d_in[1];
  const float* emb_ema    = (const float*)d_in[2];
  const float* counts_ema = (const float*)d_in[3];
  float* out = (float*)d_out;
  float* ws  = (float*)d_ws;

  vq_prep<<<16, 256, 0, stream>>>(emb, ws);
  vq_main<<<512, 256, 0, stream>>>(z_e, ws + W_G16H, ws + W_G16L,
                                   ws + W_EMBT, ws + W_EN2, ws + W_EMAXA,
                                   ws + W_UPD, ws + W_CNT,
                                   (int*)(ws + W_FLAGN), (int*)(ws + W_FLAGL), out);
  vq_rescore_final<<<256, 256, 0, stream>>>(z_e, ws + W_EMBT, ws + W_ENORM,
                                            (int*)(ws + W_FLAGN), (int*)(ws + W_FLAGL),
                                            ws + W_UPD, ws + W_CNT,
                                            emb_ema, counts_ema,
                                            (int*)(ws + W_DONE), out);
}

// Round 4
// 152.494 us; speedup vs baseline: 1.6591x; 1.6591x over previous
//
#include <hip/hip_runtime.h>
#include <math.h>

// Problem constants
#define KCODES 1024
#define DDIM   64

// Output layout (floats), reference return order.
constexpr size_t O_ZQ  = 0;
constexpr size_t O_IDX = 4194304;
constexpr size_t O_EMB = O_IDX + 65536;   // 4259840
constexpr size_t O_EMA = O_EMB + 65536;   // 4325376
constexpr size_t O_CEN = O_EMA + 65536;   // 4390912

// Workspace layout (float offsets)
constexpr size_t W_UPD   = 0;               // [K][D] segment-sum accumulator
constexpr size_t W_CNT   = 65536;           // [K] histogram
constexpr size_t W_ENORM = 66560;           // [K] ||e_k||^2 (fp32 exact)
constexpr size_t W_EN2   = 67584;           // [K] -0.5*||e_k||^2 (acc-init fold)
constexpr size_t W_EMAXA = 68608;           // [16] per-prep-block max ||e||^2
constexpr size_t W_FLAGN = 68624;           // int: ambiguous-row count
constexpr size_t W_FLAGL = 68656;           // [FLAGCAP] int row ids
constexpr int    FLAGCAP = 8192;
constexpr size_t W_EMBT  = 76848;           // [K][D] codebook fp32 (transposed)
constexpr size_t W_G16H  = 142384;          // [16 chunks][64 codes][64d] f16 hi, PRE-SWIZZLED
constexpr size_t W_G16L  = 175152;          // same, f16 lo. end = 207920 floats

typedef _Float16 f16;
typedef f16 f16x8 __attribute__((ext_vector_type(8)));
typedef float f32x4 __attribute__((ext_vector_type(4)));

#define MF(a, b, c) __builtin_amdgcn_mfma_f32_16x16x32_f16((a), (b), (c), 0, 0, 0)

static __device__ __forceinline__ void gload16(const void* g, void* l) {
  __builtin_amdgcn_global_load_lds(
      (const __attribute__((address_space(1))) void*)g,
      (__attribute__((address_space(3))) void*)l, 16, 0, 0);
}

// ---------------------------------------------------------------------------
// K1: transpose emb -> embT fp32; f16 hi/lo split written PRE-SWIZZLED so a
// linear global_load_lds copy yields the XOR-swizzled LDS image (m173
// pattern); eNorm, en2=-0.5*eNorm, per-block emax; zero upd/cnt/flagn.
__global__ __launch_bounds__(256) void vq_prep(const float* __restrict__ emb,
                                               float* __restrict__ ws) {
  __shared__ float t_lds[64 * 65];          // [d][k] padded (+1)
  const int tid = threadIdx.x;
  const int g   = blockIdx.x;
  const int k0  = g * 64;

  #pragma unroll
  for (int it = 0; it < 16; ++it) {
    const int idx = tid + it * 256;         // 0..4095
    const int d   = idx >> 6;
    const int kq  = idx & 63;
    t_lds[d * 65 + kq] = emb[d * KCODES + k0 + kq];
  }
  __syncthreads();

  f16* gh = (f16*)(ws + W_G16H);
  f16* gl = (f16*)(ws + W_G16L);
  #pragma unroll
  for (int it = 0; it < 16; ++it) {
    const int idx = tid + it * 256;
    const int kk  = idx >> 6;               // local code 0..63
    const int d   = idx & 63;
    const float v = t_lds[d * 65 + kk];
    ws[W_EMBT + (size_t)(k0 + kk) * 64 + d] = v;
    const f16 hi = (f16)v;
    const f16 lo = (f16)(v - (float)hi);
    // swizzled 16B-unit index: u = (d>>3) ^ (kk&7)
    const int u  = (d >> 3) ^ (kk & 7);
    const size_t fo = (size_t)g * 4096 + kk * 64 + u * 8 + (d & 7);
    gh[fo] = hi;
    gl[fo] = lo;
  }

  if (tid < 64) {
    const int k = tid;
    float s = 0.f;
    #pragma unroll
    for (int d = 0; d < DDIM; ++d) {
      const float v = t_lds[d * 65 + k];
      s = fmaf(v, v, s);
    }
    ws[W_ENORM + k0 + k] = s;
    ws[W_EN2   + k0 + k] = -0.5f * s;
    float mx = s;
    #pragma unroll
    for (int off = 1; off < 64; off <<= 1) mx = fmaxf(mx, __shfl_xor(mx, off, 64));
    if (tid == 0) ws[W_EMAXA + g] = mx;
  }

  float4* u4 = (float4*)(ws + W_UPD);
  #pragma unroll
  for (int j = 0; j < 4; ++j) u4[g * 1024 + tid + j * 256] = float4{0.f, 0.f, 0.f, 0.f};
  if (tid < 64) ws[W_CNT + k0 + tid] = 0.f;
  if (g == 0 && tid == 0) ((int*)(ws + W_FLAGN))[0] = 0;
}

// ---------------------------------------------------------------------------
// K2: MFMA distance GEMM (3-term f16 split) + certified argmin + fused
// epilogue. 512 blocks x 256 thr; block = 128 rows x full K. Each wave owns
// TWO 16-row sets sharing one set of A-frag LDS reads. e-tiles: 64-code
// chunks, double-buffered, staged via global_load_lds from the pre-swizzled
// global tables; ONE barrier per chunk, next chunk's loads issued before
// compute. en2 folded into acc init -> argmin == max(acc). Margin: accept
// iff 2*(M1-M2) > 1e-4*||z||*sqrt(emax); else defer to exact rescore.
#define ZP 132
__global__ __launch_bounds__(256, 2) void vq_main(
    const float* __restrict__ z_e,
    const float* __restrict__ g16h,   // ws + W_G16H (pre-swizzled f16 hi)
    const float* __restrict__ g16l,   // ws + W_G16L (pre-swizzled f16 lo)
    const float* __restrict__ embT,   // ws + W_EMBT [K][D] fp32 (epilogue A)
    const float* __restrict__ en2,    // ws + W_EN2  [K]
    const float* __restrict__ emaxa,  // ws + W_EMAXA [16]
    float* __restrict__ upd,
    float* __restrict__ cnt,
    int*   __restrict__ flagn,
    int*   __restrict__ flagl,
    float* __restrict__ out) {
  __shared__ float z_lds[DDIM * ZP];                 // [d][row], fp32
  __shared__ __align__(16) f16 e_hi[2][4096];        // dbuf: 64 codes x 64d
  __shared__ __align__(16) f16 e_lo[2][4096];
  __shared__ __align__(16) float en2_lds[KCODES];    // -0.5*||e||^2, all codes
  __shared__ int bidx[128];

  const int tid  = threadIdx.x;
  const int bid  = blockIdx.x;
  const int wv   = tid >> 6;
  const int lane = tid & 63;
  const int m    = lane & 15;
  const int q    = lane >> 4;
  const int r0   = wv * 32 + m;        // set0 row
  const int r1   = r0 + 16;            // set1 row

  const int n0  = bid * 128;
  const int b   = n0 >> 12;
  const int hw0 = n0 & 4095;
  const size_t zbase = (size_t)b * 262144 + (size_t)hw0;

  // ---- issue chunk-0 e-loads first (overlap with z staging) ----
  {
    const char* sh = (const char*)g16h + (size_t)(wv * 2) * 1024 + lane * 16;
    const char* sl = (const char*)g16l + (size_t)(wv * 2) * 1024 + lane * 16;
    char* dh = (char*)&e_hi[0][0] + (wv * 2) * 1024;
    char* dl = (char*)&e_lo[0][0] + (wv * 2) * 1024;
    gload16(sh, dh);           gload16(sh + 1024, dh + 1024);
    gload16(sl, dl);           gload16(sl + 1024, dl + 1024);
  }

  // ---- stage z tile [64d][128r] fp32 (coalesced), kept for epilogues ----
  {
    const float4* z4 = (const float4*)(z_e + zbase);
    #pragma unroll
    for (int it = 0; it < 8; ++it) {
      const int f  = tid + it * 256;   // 0..2047
      const int d  = f >> 5;
      const int r4 = f & 31;
      const float4 v = z4[(size_t)d * 1024 + r4];
      *(float4*)(z_lds + d * ZP + r4 * 4) = v;
    }
  }
  // ---- stage en2 (all 1024 codes, 4KB) ----
  ((float4*)en2_lds)[tid] = ((const float4*)en2)[tid];

  // ---- emax (global max over codebook, precomputed per prep-block) ----
  float emax = 0.f;
  {
    const float4* e4 = (const float4*)emaxa;
    #pragma unroll
    for (int i = 0; i < 4; ++i) {
      const float4 v = e4[i];
      emax = fmaxf(emax, fmaxf(fmaxf(v.x, v.y), fmaxf(v.z, v.w)));
    }
  }
  __syncthreads();   // z_lds + en2_lds + chunk0 ready (implicit vmcnt(0))

  // ---- build B-frags hi/lo for both row-sets + exact row norms ----
  f16x8 b0h_0, b1h_0, b0l_0, b1l_0, b0h_1, b1h_1, b0l_1, b1l_1;
  float zz0 = 0.f, zz1 = 0.f;
  #pragma unroll
  for (int j = 0; j < 8; ++j) {
    const int d0 = q * 8 + j, d1 = 32 + q * 8 + j;
    const float v00 = z_lds[d0 * ZP + r0];
    const float v01 = z_lds[d1 * ZP + r0];
    const float v10 = z_lds[d0 * ZP + r1];
    const float v11 = z_lds[d1 * ZP + r1];
    zz0 = fmaf(v00, v00, zz0); zz0 = fmaf(v01, v01, zz0);
    zz1 = fmaf(v10, v10, zz1); zz1 = fmaf(v11, v11, zz1);
    const f16 h00 = (f16)v00, h01 = (f16)v01, h10 = (f16)v10, h11 = (f16)v11;
    b0h_0[j] = h00; b1h_0[j] = h01; b0h_1[j] = h10; b1h_1[j] = h11;
    b0l_0[j] = (f16)(v00 - (float)h00);
    b1l_0[j] = (f16)(v01 - (float)h01);
    b0l_1[j] = (f16)(v10 - (float)h10);
    b1l_1[j] = (f16)(v11 - (float)h11);
  }
  zz0 += __shfl_xor(zz0, 16, 64); zz0 += __shfl_xor(zz0, 32, 64);
  zz1 += __shfl_xor(zz1, 16, 64); zz1 += __shfl_xor(zz1, 32, 64);

  // A-frag swizzled byte offsets (code m within 16-tile; units q and 4+q)
  const int lcl7  = m & 7;
  const int aoff0 = m * 128 + ((q)     ^ lcl7) * 16;
  const int aoff1 = m * 128 + ((4 + q) ^ lcl7) * 16;

  float M1_0 = -INFINITY, M2_0 = -INFINITY, M1_1 = -INFINITY, M2_1 = -INFINITY;
  int   I1_0 = 0, I1_1 = 0;

  #pragma unroll 1
  for (int c = 0; c < 16; ++c) {
    const int cb = c & 1;
    if (c < 15) {   // issue next chunk's loads (land before end-of-iter barrier)
      const int nb = cb ^ 1;
      const size_t so = (size_t)(c + 1) * 8192 + (wv * 2) * 1024 + lane * 16;
      const char* sh = (const char*)g16h + so;
      const char* sl = (const char*)g16l + so;
      char* dh = (char*)&e_hi[nb][0] + (wv * 2) * 1024;
      char* dl = (char*)&e_lo[nb][0] + (wv * 2) * 1024;
      gload16(sh, dh);           gload16(sh + 1024, dh + 1024);
      gload16(sl, dl);           gload16(sl + 1024, dl + 1024);
    }
    const char* eb = (const char*)&e_hi[cb][0];
    const char* lb = (const char*)&e_lo[cb][0];
    __builtin_amdgcn_s_setprio(1);
    #pragma unroll
    for (int t = 0; t < 4; ++t) {
      const f16x8 a0h = *(const f16x8*)(eb + t * 2048 + aoff0);
      const f16x8 a1h = *(const f16x8*)(eb + t * 2048 + aoff1);
      const f16x8 a0l = *(const f16x8*)(lb + t * 2048 + aoff0);
      const f16x8 a1l = *(const f16x8*)(lb + t * 2048 + aoff1);
      const f32x4 en2f = *(const f32x4*)(en2_lds + c * 64 + t * 16 + q * 4);
      f32x4 acc0 = en2f, acc1 = en2f;
      acc0 = MF(a0l, b0h_0, acc0);  acc1 = MF(a0l, b0h_1, acc1);
      acc0 = MF(a1l, b1h_0, acc0);  acc1 = MF(a1l, b1h_1, acc1);
      acc0 = MF(a0h, b0l_0, acc0);  acc1 = MF(a0h, b0l_1, acc1);
      acc0 = MF(a1h, b1l_0, acc0);  acc1 = MF(a1h, b1l_1, acc1);
      acc0 = MF(a0h, b0h_0, acc0);  acc1 = MF(a0h, b0h_1, acc1);
      acc0 = MF(a1h, b1h_0, acc0);  acc1 = MF(a1h, b1h_1, acc1);
      const int ib = c * 64 + t * 16 + q * 4;
      #pragma unroll
      for (int r = 0; r < 4; ++r) {
        const float a = acc0[r];
        const bool gt = a > M1_0;
        M2_0 = fmaxf(M2_0, fminf(a, M1_0));
        if (gt) I1_0 = ib + r;
        M1_0 = fmaxf(M1_0, a);
        const float a1v = acc1[r];
        const bool gt1 = a1v > M1_1;
        M2_1 = fmaxf(M2_1, fminf(a1v, M1_1));
        if (gt1) I1_1 = ib + r;
        M1_1 = fmaxf(M1_1, a1v);
      }
    }
    __builtin_amdgcn_s_setprio(0);
    __syncthreads();   // drains next-chunk loads; protects dbuf swap
  }

  // ---- merge (M1,I1,M2) across the 4 code-subgroups (lane bits 4,5) ----
  #pragma unroll
  for (int off = 16; off <= 32; off <<= 1) {
    {
      const float o1 = __shfl_xor(M1_0, off, 64);
      const float o2 = __shfl_xor(M2_0, off, 64);
      const int   oi = __shfl_xor(I1_0, off, 64);
      const float nm2 = fmaxf(fmaxf(M2_0, o2), fminf(M1_0, o1));
      if (o1 > M1_0) I1_0 = oi;
      M1_0 = fmaxf(M1_0, o1);
      M2_0 = nm2;
    }
    {
      const float o1 = __shfl_xor(M1_1, off, 64);
      const float o2 = __shfl_xor(M2_1, off, 64);
      const int   oi = __shfl_xor(I1_1, off, 64);
      const float nm2 = fmaxf(fmaxf(M2_1, o2), fminf(M1_1, o1));
      if (o1 > M1_1) I1_1 = oi;
      M1_1 = fmaxf(M1_1, o1);
      M2_1 = nm2;
    }
  }

  if (lane < 32) {   // lanes 0..15 write set0 rows, 16..31 write set1 rows
    const int s   = lane >> 4;
    const int row = wv * 32 + s * 16 + m;
    const float MM1 = s ? M1_1 : M1_0;
    const float MM2 = s ? M2_1 : M2_0;
    const int   II  = s ? I1_1 : I1_0;
    const float zzv = s ? zz1 : zz0;
    // dist gap = 2*(M1-M2); accept iff > 1e-4*||z||*sqrt(emax)
    const float Mh = 5.0e-5f * sqrtf(zzv * emax);
    if (MM1 - MM2 > Mh) {
      bidx[row] = II;
      out[O_IDX + n0 + row] = (float)II;
      atomicAdd(cnt + II, 1.0f);
    } else {
      bidx[row] = -1;                     // defer to exact rescore
      const int sl = atomicAdd(flagn, 1);
      if (sl < FLAGCAP) flagl[sl] = n0 + row;
    }
  }
  __syncthreads();

  // ---- epilogue A: z_q = z + (e - z); coalesced over rows ----
  {
    const int row  = tid & 127;
    const int half = tid >> 7;            // 2 halves x 32 d
    const int code = bidx[row];
    if (code >= 0) {
      const float4* er4 = (const float4*)(embT + (size_t)code * 64);
      #pragma unroll
      for (int qq = 0; qq < 8; ++qq) {
        const float4 e4 = er4[half * 8 + qq];
        const float ev[4] = {e4.x, e4.y, e4.z, e4.w};
        #pragma unroll
        for (int x = 0; x < 4; ++x) {
          const int d = half * 32 + qq * 4 + x;
          const float zv = z_lds[d * ZP + row];
          out[O_ZQ + zbase + (size_t)d * 4096 + row] = zv + (ev[x] - zv);
        }
      }
    }
  }

  // ---- epilogue B: segment-sum; one coalesced atomic instr per row ----
  {
    #pragma unroll 4
    for (int rr = 0; rr < 32; ++rr) {
      const int row  = wv * 32 + rr;
      const int code = bidx[row];
      if (code >= 0)
        atomicAdd(upd + (size_t)code * 64 + lane, z_lds[lane * ZP + row]);
    }
  }
}

// ---------------------------------------------------------------------------
// K3: exact fp32 rescore, one row per block, codes-parallel (256 thr x 4
// contiguous codes). Lexicographic (dist, idx) reduction reproduces the
// reference lowest-index tie rule. Completes idx/z_q/hist/segment-sum.
__global__ __launch_bounds__(256) void vq_rescore(
    const float* __restrict__ z_e,
    const float* __restrict__ embT,
    const float* __restrict__ eN,
    const int* __restrict__ flagn,
    const int* __restrict__ flagl,
    float* __restrict__ upd,
    float* __restrict__ cnt,
    float* __restrict__ out) {
  __shared__ float zrow[64];
  __shared__ float wv_v[4];
  __shared__ int   wv_i[4];
  __shared__ int   bestc;

  const int tid = threadIdx.x;
  int nf = *flagn;
  if (nf > FLAGCAP) nf = FLAGCAP;

  for (int j = blockIdx.x; j < nf; j += gridDim.x) {
    __syncthreads();   // protect zrow/bestc reuse across iterations
    const int rowid = flagl[j];
    const int bb = rowid >> 12;
    const int hw = rowid & 4095;
    const size_t base = (size_t)bb * 262144 + (size_t)hw;
    if (tid < 64) zrow[tid] = z_e[base + (size_t)tid * 4096];
    __syncthreads();

    // 4 ascending codes per thread; strict < keeps lowest index
    float bm = INFINITY;
    int   bi = 0;
    #pragma unroll
    for (int cc = 0; cc < 4; ++cc) {
      const int k = tid * 4 + cc;
      const float4* e4p = (const float4*)(embT + (size_t)k * 64);
      float a0 = 0.f, a1 = 0.f, a2 = 0.f, a3 = 0.f;
      #pragma unroll
      for (int d4 = 0; d4 < 16; ++d4) {
        const float4 e4 = e4p[d4];
        a0 = fmaf(zrow[d4 * 4 + 0], e4.x, a0);
        a1 = fmaf(zrow[d4 * 4 + 1], e4.y, a1);
        a2 = fmaf(zrow[d4 * 4 + 2], e4.z, a2);
        a3 = fmaf(zrow[d4 * 4 + 3], e4.w, a3);
      }
      const float dist = fmaf(-2.f, (a0 + a1) + (a2 + a3), eN[k]);
      if (dist < bm) { bm = dist; bi = k; }
    }
    #pragma unroll
    for (int mm = 1; mm < 64; mm <<= 1) {
      const float v2 = __shfl_xor(bm, mm, 64);
      const int   i2 = __shfl_xor(bi, mm, 64);
      if (v2 < bm || (v2 == bm && i2 < bi)) { bm = v2; bi = i2; }
    }
    if ((tid & 63) == 0) { wv_v[tid >> 6] = bm; wv_i[tid >> 6] = bi; }
    __syncthreads();
    if (tid == 0) {
      float v = wv_v[0]; int ix = wv_i[0];
      #pragma unroll
      for (int w = 1; w < 4; ++w) {
        if (wv_v[w] < v || (wv_v[w] == v && wv_i[w] < ix)) { v = wv_v[w]; ix = wv_i[w]; }
      }
      bestc = ix;
      out[O_IDX + rowid] = (float)ix;
      atomicAdd(cnt + ix, 1.0f);
    }
    __syncthreads();
    if (tid < 64) {
      const int d = tid;
      const float zv = zrow[d];
      const float ev = embT[(size_t)bestc * 64 + d];
      out[O_ZQ + base + (size_t)d * 4096] = zv + (ev - zv);
      atomicAdd(upd + (size_t)bestc * 64 + d, zv);
    }
  }
}

// ---------------------------------------------------------------------------
// K4: EMA updates + normalization. 256 blocks; each redundantly reduces n.
__global__ __launch_bounds__(256) void vq_final(const float* __restrict__ emb_ema,
                                                const float* __restrict__ counts_ema,
                                                const float* __restrict__ ws,
                                                float* __restrict__ out) {
  __shared__ float red[256];
  const int tid = threadIdx.x;
  const float* cnt = ws + W_CNT;

  float psum = 0.f;
  for (int t = tid; t < KCODES; t += 256) {
    const float ce  = counts_ema[t];
    const float cen = ce + 0.01f * (cnt[t] - ce);
    psum += cen;
    if (blockIdx.x == 0) out[O_CEN + t] = cen;
  }
  red[tid] = psum;
  __syncthreads();
  #pragma unroll
  for (int s = 128; s > 0; s >>= 1) {
    if (tid < s) red[tid] += red[tid + s];
    __syncthreads();
  }
  const float nsum = red[0];

  const int i = blockIdx.x * 256 + tid;   // 0..65535 over [D][K]
  const int d = i >> 10;
  const int k = i & 1023;

  const float ce  = counts_ema[k];
  const float cen = ce + 0.01f * (cnt[k] - ce);
  const float norm = (cen + 1e-5f) / (nsum + (float)KCODES * 1e-5f) * nsum;

  const float ema     = emb_ema[i];
  const float ema_new = ema + 0.01f * (ws[W_UPD + (size_t)k * 64 + d] - ema);
  out[O_EMA + i] = ema_new;
  out[O_EMB + i] = ema_new / norm;
}

// ---------------------------------------------------------------------------
extern "C" void kernel_launch(void* const* d_in, const int* in_sizes, int n_in,
                              void* d_out, int out_size, void* d_ws, size_t ws_size,
                              hipStream_t stream) {
  const float* z_e        = (const float*)d_in[0];
  const float* emb        = (const float*)d_in[1];
  const float* emb_ema    = (const float*)d_in[2];
  const float* counts_ema = (const float*)d_in[3];
  float* out = (float*)d_out;
  float* ws  = (float*)d_ws;

  vq_prep<<<16, 256, 0, stream>>>(emb, ws);
  vq_main<<<512, 256, 0, stream>>>(z_e, ws + W_G16H, ws + W_G16L,
                                   ws + W_EMBT, ws + W_EN2, ws + W_EMAXA,
                                   ws + W_UPD, ws + W_CNT,
                                   (int*)(ws + W_FLAGN), (int*)(ws + W_FLAGL), out);
  vq_rescore<<<256, 256, 0, stream>>>(z_e, ws + W_EMBT, ws + W_ENORM,
                                      (int*)(ws + W_FLAGN), (int*)(ws + W_FLAGL),
                                      ws + W_UPD, ws + W_CNT, out);
  vq_final<<<256, 256, 0, stream>>>(emb_ema, counts_ema, ws, out);
}

// Round 5
// 137.466 us; speedup vs baseline: 1.8405x; 1.1093x over previous
//
#include <hip/hip_runtime.h>
#include <math.h>

// Problem constants
#define KCODES 1024
#define DDIM   64
#define NCOPY  4          // privatized atomic table copies

// Output layout (floats), reference return order.
constexpr size_t O_ZQ  = 0;
constexpr size_t O_IDX = 4194304;
constexpr size_t O_EMB = O_IDX + 65536;   // 4259840
constexpr size_t O_EMA = O_EMB + 65536;   // 4325376
constexpr size_t O_CEN = O_EMA + 65536;   // 4390912

// Workspace layout (float offsets)
constexpr size_t W_UPD   = 0;               // [NCOPY][K][64] segment-sum copies
constexpr size_t W_CNT   = 262144;          // [NCOPY][K] histogram copies
constexpr size_t W_ENORM = 266240;          // [K] ||e_k||^2 (fp32 exact)
constexpr size_t W_EN2   = 267264;          // [K] -0.5*||e_k||^2 (acc-init fold)
constexpr size_t W_EMAXA = 268288;          // [16] per-prep-block max ||e||^2
constexpr size_t W_FLAGN = 268304;          // int: ambiguous-row count
constexpr size_t W_FLAGL = 268320;          // [FLAGCAP] int row ids
constexpr int    FLAGCAP = 8192;
constexpr size_t W_EMBT  = 276512;          // [K][D] codebook fp32 (transposed)
constexpr size_t W_G16H  = 342048;          // [16 chunks][64 codes][64d] f16 hi, PRE-SWIZZLED
constexpr size_t W_G16L  = 374816;          // same, f16 lo. end = 407584 floats

typedef _Float16 f16;
typedef f16 f16x8 __attribute__((ext_vector_type(8)));
typedef float f32x4 __attribute__((ext_vector_type(4)));

#define MF(a, b, c) __builtin_amdgcn_mfma_f32_16x16x32_f16((a), (b), (c), 0, 0, 0)

static __device__ __forceinline__ void gload16(const void* g, void* l) {
  __builtin_amdgcn_global_load_lds(
      (const __attribute__((address_space(1))) void*)g,
      (__attribute__((address_space(3))) void*)l, 16, 0, 0);
}

// ---------------------------------------------------------------------------
// K1: 64 blocks. Blocks 0-15: transpose emb -> embT fp32; f16 hi/lo split
// written PRE-SWIZZLED (linear global_load_lds copy yields swizzled LDS
// image); eNorm, en2, per-block emax. ALL 64 blocks: zero the privatized
// upd/cnt copies (1.04 MB) in parallel.
__global__ __launch_bounds__(256) void vq_prep(const float* __restrict__ emb,
                                               float* __restrict__ ws) {
  __shared__ float t_lds[64 * 65];          // [d][k] padded (+1)
  const int tid = threadIdx.x;
  const int g   = blockIdx.x;

  if (g < 16) {
    const int k0 = g * 64;
    #pragma unroll
    for (int it = 0; it < 16; ++it) {
      const int idx = tid + it * 256;       // 0..4095
      const int d   = idx >> 6;
      const int kq  = idx & 63;
      t_lds[d * 65 + kq] = emb[d * KCODES + k0 + kq];
    }
    __syncthreads();

    f16* gh = (f16*)(ws + W_G16H);
    f16* gl = (f16*)(ws + W_G16L);
    #pragma unroll
    for (int it = 0; it < 16; ++it) {
      const int idx = tid + it * 256;
      const int kk  = idx >> 6;             // local code 0..63
      const int d   = idx & 63;
      const float v = t_lds[d * 65 + kk];
      ws[W_EMBT + (size_t)(k0 + kk) * 64 + d] = v;
      const f16 hi = (f16)v;
      const f16 lo = (f16)(v - (float)hi);
      // swizzled 16B-unit index: u = (d>>3) ^ (kk&7)
      const int u  = (d >> 3) ^ (kk & 7);
      const size_t fo = (size_t)g * 4096 + kk * 64 + u * 8 + (d & 7);
      gh[fo] = hi;
      gl[fo] = lo;
    }

    if (tid < 64) {
      const int k = tid;
      float s = 0.f;
      #pragma unroll
      for (int d = 0; d < DDIM; ++d) {
        const float v = t_lds[d * 65 + k];
        s = fmaf(v, v, s);
      }
      ws[W_ENORM + k0 + k] = s;
      ws[W_EN2   + k0 + k] = -0.5f * s;
      float mx = s;
      #pragma unroll
      for (int off = 1; off < 64; off <<= 1) mx = fmaxf(mx, __shfl_xor(mx, off, 64));
      if (tid == 0) ws[W_EMAXA + g] = mx;
    }
  }

  // ---- zero privatized upd+cnt copies (contiguous [0, 266240) floats) ----
  {
    float4* base = (float4*)(ws + W_UPD);
    const int total4 = 66560;               // 266240/4
    for (int idx = g * 256 + tid; idx < total4; idx += 64 * 256)
      base[idx] = float4{0.f, 0.f, 0.f, 0.f};
  }
  if (g == 0 && tid == 0) ((int*)(ws + W_FLAGN))[0] = 0;
}

// ---------------------------------------------------------------------------
// K2: MFMA distance GEMM (3-term f16 split) + certified argmin + fused
// epilogue. 512 blocks x 256 thr; block = 128 rows x full K. Each wave owns
// TWO 16-row sets sharing one set of A-frag LDS reads. e-tiles: 64-code
// chunks, double-buffered, staged via global_load_lds from the pre-swizzled
// global tables; ONE barrier per chunk, next chunk's loads issued before
// compute. en2 folded into acc init -> argmin == max(acc). Margin: accept
// iff 2*(M1-M2) > 1e-4*||z||*sqrt(emax); else defer to exact rescore.
// Atomics go to private copy (bid & (NCOPY-1)) to cut hot-line contention.
#define ZP 132
__global__ __launch_bounds__(256, 2) void vq_main(
    const float* __restrict__ z_e,
    const float* __restrict__ g16h,   // ws + W_G16H (pre-swizzled f16 hi)
    const float* __restrict__ g16l,   // ws + W_G16L (pre-swizzled f16 lo)
    const float* __restrict__ embT,   // ws + W_EMBT [K][D] fp32 (epilogue A)
    const float* __restrict__ en2,    // ws + W_EN2  [K]
    const float* __restrict__ emaxa,  // ws + W_EMAXA [16]
    float* __restrict__ upd,          // base of NCOPY copies
    float* __restrict__ cnt,          // base of NCOPY copies
    int*   __restrict__ flagn,
    int*   __restrict__ flagl,
    float* __restrict__ out) {
  __shared__ float z_lds[DDIM * ZP];                 // [d][row], fp32
  __shared__ __align__(16) f16 e_hi[2][4096];        // dbuf: 64 codes x 64d
  __shared__ __align__(16) f16 e_lo[2][4096];
  __shared__ __align__(16) float en2_lds[KCODES];    // -0.5*||e||^2, all codes
  __shared__ int bidx[128];

  const int tid  = threadIdx.x;
  const int bid  = blockIdx.x;
  const int wv   = tid >> 6;
  const int lane = tid & 63;
  const int m    = lane & 15;
  const int q    = lane >> 4;
  const int r0   = wv * 32 + m;        // set0 row
  const int r1   = r0 + 16;            // set1 row

  float* updc = upd + ((size_t)(bid & (NCOPY - 1)) << 16);  // copy base
  float* cntc = cnt + ((size_t)(bid & (NCOPY - 1)) << 10);

  const int n0  = bid * 128;
  const int b   = n0 >> 12;
  const int hw0 = n0 & 4095;
  const size_t zbase = (size_t)b * 262144 + (size_t)hw0;

  // ---- issue chunk-0 e-loads first (overlap with z staging) ----
  {
    const char* sh = (const char*)g16h + (size_t)(wv * 2) * 1024 + lane * 16;
    const char* sl = (const char*)g16l + (size_t)(wv * 2) * 1024 + lane * 16;
    char* dh = (char*)&e_hi[0][0] + (wv * 2) * 1024;
    char* dl = (char*)&e_lo[0][0] + (wv * 2) * 1024;
    gload16(sh, dh);           gload16(sh + 1024, dh + 1024);
    gload16(sl, dl);           gload16(sl + 1024, dl + 1024);
  }

  // ---- stage z tile [64d][128r] fp32 (coalesced), kept for epilogues ----
  {
    const float4* z4 = (const float4*)(z_e + zbase);
    #pragma unroll
    for (int it = 0; it < 8; ++it) {
      const int f  = tid + it * 256;   // 0..2047
      const int d  = f >> 5;
      const int r4 = f & 31;
      const float4 v = z4[(size_t)d * 1024 + r4];
      *(float4*)(z_lds + d * ZP + r4 * 4) = v;
    }
  }
  // ---- stage en2 (all 1024 codes, 4KB) ----
  ((float4*)en2_lds)[tid] = ((const float4*)en2)[tid];

  // ---- emax (global max over codebook, precomputed per prep-block) ----
  float emax = 0.f;
  {
    const float4* e4 = (const float4*)emaxa;
    #pragma unroll
    for (int i = 0; i < 4; ++i) {
      const float4 v = e4[i];
      emax = fmaxf(emax, fmaxf(fmaxf(v.x, v.y), fmaxf(v.z, v.w)));
    }
  }
  __syncthreads();   // z_lds + en2_lds + chunk0 ready (implicit vmcnt(0))

  // ---- build B-frags hi/lo for both row-sets + exact row norms ----
  f16x8 b0h_0, b1h_0, b0l_0, b1l_0, b0h_1, b1h_1, b0l_1, b1l_1;
  float zz0 = 0.f, zz1 = 0.f;
  #pragma unroll
  for (int j = 0; j < 8; ++j) {
    const int d0 = q * 8 + j, d1 = 32 + q * 8 + j;
    const float v00 = z_lds[d0 * ZP + r0];
    const float v01 = z_lds[d1 * ZP + r0];
    const float v10 = z_lds[d0 * ZP + r1];
    const float v11 = z_lds[d1 * ZP + r1];
    zz0 = fmaf(v00, v00, zz0); zz0 = fmaf(v01, v01, zz0);
    zz1 = fmaf(v10, v10, zz1); zz1 = fmaf(v11, v11, zz1);
    const f16 h00 = (f16)v00, h01 = (f16)v01, h10 = (f16)v10, h11 = (f16)v11;
    b0h_0[j] = h00; b1h_0[j] = h01; b0h_1[j] = h10; b1h_1[j] = h11;
    b0l_0[j] = (f16)(v00 - (float)h00);
    b1l_0[j] = (f16)(v01 - (float)h01);
    b0l_1[j] = (f16)(v10 - (float)h10);
    b1l_1[j] = (f16)(v11 - (float)h11);
  }
  zz0 += __shfl_xor(zz0, 16, 64); zz0 += __shfl_xor(zz0, 32, 64);
  zz1 += __shfl_xor(zz1, 16, 64); zz1 += __shfl_xor(zz1, 32, 64);

  // A-frag swizzled byte offsets (code m within 16-tile; units q and 4+q)
  const int lcl7  = m & 7;
  const int aoff0 = m * 128 + ((q)     ^ lcl7) * 16;
  const int aoff1 = m * 128 + ((4 + q) ^ lcl7) * 16;

  float M1_0 = -INFINITY, M2_0 = -INFINITY, M1_1 = -INFINITY, M2_1 = -INFINITY;
  int   I1_0 = 0, I1_1 = 0;

  #pragma unroll 1
  for (int c = 0; c < 16; ++c) {
    const int cb = c & 1;
    if (c < 15) {   // issue next chunk's loads (land before end-of-iter barrier)
      const int nb = cb ^ 1;
      const size_t so = (size_t)(c + 1) * 8192 + (wv * 2) * 1024 + lane * 16;
      const char* sh = (const char*)g16h + so;
      const char* sl = (const char*)g16l + so;
      char* dh = (char*)&e_hi[nb][0] + (wv * 2) * 1024;
      char* dl = (char*)&e_lo[nb][0] + (wv * 2) * 1024;
      gload16(sh, dh);           gload16(sh + 1024, dh + 1024);
      gload16(sl, dl);           gload16(sl + 1024, dl + 1024);
    }
    const char* eb = (const char*)&e_hi[cb][0];
    const char* lb = (const char*)&e_lo[cb][0];
    __builtin_amdgcn_s_setprio(1);
    #pragma unroll
    for (int t = 0; t < 4; ++t) {
      const f16x8 a0h = *(const f16x8*)(eb + t * 2048 + aoff0);
      const f16x8 a1h = *(const f16x8*)(eb + t * 2048 + aoff1);
      const f16x8 a0l = *(const f16x8*)(lb + t * 2048 + aoff0);
      const f16x8 a1l = *(const f16x8*)(lb + t * 2048 + aoff1);
      const f32x4 en2f = *(const f32x4*)(en2_lds + c * 64 + t * 16 + q * 4);
      f32x4 acc0 = en2f, acc1 = en2f;
      acc0 = MF(a0l, b0h_0, acc0);  acc1 = MF(a0l, b0h_1, acc1);
      acc0 = MF(a1l, b1h_0, acc0);  acc1 = MF(a1l, b1h_1, acc1);
      acc0 = MF(a0h, b0l_0, acc0);  acc1 = MF(a0h, b0l_1, acc1);
      acc0 = MF(a1h, b1l_0, acc0);  acc1 = MF(a1h, b1l_1, acc1);
      acc0 = MF(a0h, b0h_0, acc0);  acc1 = MF(a0h, b0h_1, acc1);
      acc0 = MF(a1h, b1h_0, acc0);  acc1 = MF(a1h, b1h_1, acc1);
      const int ib = c * 64 + t * 16 + q * 4;
      #pragma unroll
      for (int r = 0; r < 4; ++r) {
        const float a = acc0[r];
        const bool gt = a > M1_0;
        M2_0 = fmaxf(M2_0, fminf(a, M1_0));
        if (gt) I1_0 = ib + r;
        M1_0 = fmaxf(M1_0, a);
        const float a1v = acc1[r];
        const bool gt1 = a1v > M1_1;
        M2_1 = fmaxf(M2_1, fminf(a1v, M1_1));
        if (gt1) I1_1 = ib + r;
        M1_1 = fmaxf(M1_1, a1v);
      }
    }
    __builtin_amdgcn_s_setprio(0);
    __syncthreads();   // drains next-chunk loads; protects dbuf swap
  }

  // ---- merge (M1,I1,M2) across the 4 code-subgroups (lane bits 4,5) ----
  #pragma unroll
  for (int off = 16; off <= 32; off <<= 1) {
    {
      const float o1 = __shfl_xor(M1_0, off, 64);
      const float o2 = __shfl_xor(M2_0, off, 64);
      const int   oi = __shfl_xor(I1_0, off, 64);
      const float nm2 = fmaxf(fmaxf(M2_0, o2), fminf(M1_0, o1));
      if (o1 > M1_0) I1_0 = oi;
      M1_0 = fmaxf(M1_0, o1);
      M2_0 = nm2;
    }
    {
      const float o1 = __shfl_xor(M1_1, off, 64);
      const float o2 = __shfl_xor(M2_1, off, 64);
      const int   oi = __shfl_xor(I1_1, off, 64);
      const float nm2 = fmaxf(fmaxf(M2_1, o2), fminf(M1_1, o1));
      if (o1 > M1_1) I1_1 = oi;
      M1_1 = fmaxf(M1_1, o1);
      M2_1 = nm2;
    }
  }

  if (lane < 32) {   // lanes 0..15 write set0 rows, 16..31 write set1 rows
    const int s   = lane >> 4;
    const int row = wv * 32 + s * 16 + m;
    const float MM1 = s ? M1_1 : M1_0;
    const float MM2 = s ? M2_1 : M2_0;
    const int   II  = s ? I1_1 : I1_0;
    const float zzv = s ? zz1 : zz0;
    // dist gap = 2*(M1-M2); accept iff > 1e-4*||z||*sqrt(emax)
    const float Mh = 5.0e-5f * sqrtf(zzv * emax);
    if (MM1 - MM2 > Mh) {
      bidx[row] = II;
      out[O_IDX + n0 + row] = (float)II;
      atomicAdd(cntc + II, 1.0f);
    } else {
      bidx[row] = -1;                     // defer to exact rescore
      const int sl = atomicAdd(flagn, 1);
      if (sl < FLAGCAP) flagl[sl] = n0 + row;
    }
  }
  __syncthreads();

  // ---- epilogue A: z_q = z + (e - z); coalesced over rows ----
  {
    const int row  = tid & 127;
    const int half = tid >> 7;            // 2 halves x 32 d
    const int code = bidx[row];
    if (code >= 0) {
      const float4* er4 = (const float4*)(embT + (size_t)code * 64);
      #pragma unroll
      for (int qq = 0; qq < 8; ++qq) {
        const float4 e4 = er4[half * 8 + qq];
        const float ev[4] = {e4.x, e4.y, e4.z, e4.w};
        #pragma unroll
        for (int x = 0; x < 4; ++x) {
          const int d = half * 32 + qq * 4 + x;
          const float zv = z_lds[d * ZP + row];
          out[O_ZQ + zbase + (size_t)d * 4096 + row] = zv + (ev[x] - zv);
        }
      }
    }
  }

  // ---- epilogue B: segment-sum; one coalesced atomic instr per row ----
  {
    #pragma unroll 4
    for (int rr = 0; rr < 32; ++rr) {
      const int row  = wv * 32 + rr;
      const int code = bidx[row];
      if (code >= 0)
        atomicAdd(updc + (size_t)code * 64 + lane, z_lds[lane * ZP + row]);
    }
  }
}

// ---------------------------------------------------------------------------
// K3: exact fp32 rescore, one row per block, codes-parallel (256 thr x 4
// contiguous codes). Lexicographic (dist, idx) reduction reproduces the
// reference lowest-index tie rule. Completes idx/z_q/hist/segment-sum
// (into copy 0 of the privatized tables).
__global__ __launch_bounds__(256) void vq_rescore(
    const float* __restrict__ z_e,
    const float* __restrict__ embT,
    const float* __restrict__ eN,
    const int* __restrict__ flagn,
    const int* __restrict__ flagl,
    float* __restrict__ upd,
    float* __restrict__ cnt,
    float* __restrict__ out) {
  __shared__ float zrow[64];
  __shared__ float wv_v[4];
  __shared__ int   wv_i[4];
  __shared__ int   bestc;

  const int tid = threadIdx.x;
  int nf = *flagn;
  if (nf > FLAGCAP) nf = FLAGCAP;

  for (int j = blockIdx.x; j < nf; j += gridDim.x) {
    __syncthreads();   // protect zrow/bestc reuse across iterations
    const int rowid = flagl[j];
    const int bb = rowid >> 12;
    const int hw = rowid & 4095;
    const size_t base = (size_t)bb * 262144 + (size_t)hw;
    if (tid < 64) zrow[tid] = z_e[base + (size_t)tid * 4096];
    __syncthreads();

    // 4 ascending codes per thread; strict < keeps lowest index
    float bm = INFINITY;
    int   bi = 0;
    #pragma unroll
    for (int cc = 0; cc < 4; ++cc) {
      const int k = tid * 4 + cc;
      const float4* e4p = (const float4*)(embT + (size_t)k * 64);
      float a0 = 0.f, a1 = 0.f, a2 = 0.f, a3 = 0.f;
      #pragma unroll
      for (int d4 = 0; d4 < 16; ++d4) {
        const float4 e4 = e4p[d4];
        a0 = fmaf(zrow[d4 * 4 + 0], e4.x, a0);
        a1 = fmaf(zrow[d4 * 4 + 1], e4.y, a1);
        a2 = fmaf(zrow[d4 * 4 + 2], e4.z, a2);
        a3 = fmaf(zrow[d4 * 4 + 3], e4.w, a3);
      }
      const float dist = fmaf(-2.f, (a0 + a1) + (a2 + a3), eN[k]);
      if (dist < bm) { bm = dist; bi = k; }
    }
    #pragma unroll
    for (int mm = 1; mm < 64; mm <<= 1) {
      const float v2 = __shfl_xor(bm, mm, 64);
      const int   i2 = __shfl_xor(bi, mm, 64);
      if (v2 < bm || (v2 == bm && i2 < bi)) { bm = v2; bi = i2; }
    }
    if ((tid & 63) == 0) { wv_v[tid >> 6] = bm; wv_i[tid >> 6] = bi; }
    __syncthreads();
    if (tid == 0) {
      float v = wv_v[0]; int ix = wv_i[0];
      #pragma unroll
      for (int w = 1; w < 4; ++w) {
        if (wv_v[w] < v || (wv_v[w] == v && wv_i[w] < ix)) { v = wv_v[w]; ix = wv_i[w]; }
      }
      bestc = ix;
      out[O_IDX + rowid] = (float)ix;
      atomicAdd(cnt + ix, 1.0f);
    }
    __syncthreads();
    if (tid < 64) {
      const int d = tid;
      const float zv = zrow[d];
      const float ev = embT[(size_t)bestc * 64 + d];
      out[O_ZQ + base + (size_t)d * 4096] = zv + (ev - zv);
      atomicAdd(upd + (size_t)bestc * 64 + d, zv);
    }
  }
}

// ---------------------------------------------------------------------------
// K4: EMA updates + normalization, summing the NCOPY privatized tables.
__global__ __launch_bounds__(256) void vq_final(const float* __restrict__ emb_ema,
                                                const float* __restrict__ counts_ema,
                                                const float* __restrict__ ws,
                                                float* __restrict__ out) {
  __shared__ float red[256];
  const int tid = threadIdx.x;
  const float* cnt = ws + W_CNT;
  const float* upd = ws + W_UPD;

  float psum = 0.f;
  for (int t = tid; t < KCODES; t += 256) {
    float c = 0.f;
    #pragma unroll
    for (int p = 0; p < NCOPY; ++p) c += cnt[p * KCODES + t];
    const float ce  = counts_ema[t];
    const float cen = ce + 0.01f * (c - ce);
    psum += cen;
    if (blockIdx.x == 0) out[O_CEN + t] = cen;
  }
  red[tid] = psum;
  __syncthreads();
  #pragma unroll
  for (int s = 128; s > 0; s >>= 1) {
    if (tid < s) red[tid] += red[tid + s];
    __syncthreads();
  }
  const float nsum = red[0];

  const int i = blockIdx.x * 256 + tid;   // 0..65535 over [D][K]
  const int d = i >> 10;
  const int k = i & 1023;

  float c = 0.f;
  #pragma unroll
  for (int p = 0; p < NCOPY; ++p) c += cnt[p * KCODES + k];
  const float ce  = counts_ema[k];
  const float cen = ce + 0.01f * (c - ce);
  const float norm = (cen + 1e-5f) / (nsum + (float)KCODES * 1e-5f) * nsum;

  float us = 0.f;
  #pragma unroll
  for (int p = 0; p < NCOPY; ++p) us += upd[(size_t)p * 65536 + (size_t)k * 64 + d];
  const float ema     = emb_ema[i];
  const float ema_new = ema + 0.01f * (us - ema);
  out[O_EMA + i] = ema_new;
  out[O_EMB + i] = ema_new / norm;
}

// ---------------------------------------------------------------------------
extern "C" void kernel_launch(void* const* d_in, const int* in_sizes, int n_in,
                              void* d_out, int out_size, void* d_ws, size_t ws_size,
                              hipStream_t stream) {
  const float* z_e        = (const float*)d_in[0];
  const float* emb        = (const float*)d_in[1];
  const float* emb_ema    = (const float*)d_in[2];
  const float* counts_ema = (const float*)d_in[3];
  float* out = (float*)d_out;
  float* ws  = (float*)d_ws;

  vq_prep<<<64, 256, 0, stream>>>(emb, ws);
  vq_main<<<512, 256, 0, stream>>>(z_e, ws + W_G16H, ws + W_G16L,
                                   ws + W_EMBT, ws + W_EN2, ws + W_EMAXA,
                                   ws + W_UPD, ws + W_CNT,
                                   (int*)(ws + W_FLAGN), (int*)(ws + W_FLAGL), out);
  vq_rescore<<<256, 256, 0, stream>>>(z_e, ws + W_EMBT, ws + W_ENORM,
                                      (int*)(ws + W_FLAGN), (int*)(ws + W_FLAGL),
                                      ws + W_UPD, ws + W_CNT, out);
  vq_final<<<256, 256, 0, stream>>>(emb_ema, counts_ema, ws, out);
}